// Round 1
// baseline (338.823 us; speedup 1.0000x reference)
//
#include <hip/hip_runtime.h>

#define N_NODES 4194304
#define LEVELS  10
#define COARSE  8192
#define NNZ_E   8388608
#define NCHUNK  16384    // N_NODES / 256
#define NB      256      // row buckets == col buckets
#define CB_SZ   16384    // cols per col-bucket (32 KiB bf16 LDS slice)
#define RB_SZ   16384    // rows per row-bucket (64 KiB LDS accumulator)
#define HB      1024     // hist/binning blocks
#define EPB     8192     // edges per binning block
#define CSUB    4096     // kC binning sub-tile (32 KiB LDS -> 4 blocks/CU)
#define TILE_D  4096     // kD tile size (LDS ~54 KiB -> 2 blocks/CU)

typedef int          v4i __attribute__((ext_vector_type(4)));
typedef float        v4f __attribute__((ext_vector_type(4)));
typedef unsigned int v4u __attribute__((ext_vector_type(4)));
typedef unsigned int v2u __attribute__((ext_vector_type(2)));

static __device__ __forceinline__ unsigned short f2bf(float x) {
    unsigned u = __float_as_uint(x);
    return (unsigned short)((u + 0x7FFFu + ((u >> 16) & 1u)) >> 16);
}
static __device__ __forceinline__ float bf2f(unsigned short h) {
    return __uint_as_float((unsigned)h << 16);
}
static __device__ __forceinline__ unsigned f18(float p) {   // 1s+8e+9m, RN
    return ((__float_as_uint(p) + 0x2000u) >> 14) & 0x3FFFFu;
}

// ============ kA: HODLR moments (blocks 0..2047) + dual row/col hist (2048..3071)
__global__ __launch_bounds__(512) void kA(const float* __restrict__ z,
                                          float2* __restrict__ M,
                                          float* __restrict__ S,
                                          float* __restrict__ out,
                                          const int* __restrict__ rows,
                                          const int* __restrict__ cols,
                                          unsigned* __restrict__ colBO,
                                          unsigned* __restrict__ rowBC) {
    int b = blockIdx.x, t = threadIdx.x;
    if (b < 2048) {
        if (b == 0) {
            for (int i = t; i < 2046 * 2; i += 512) S[i] = 0.f;
            if (t == 0) out[0] = 0.f;
        }
        int lane = t & 63, wave = t >> 6;
        int chunk = b * 8 + wave;
        int base = chunk * 256 + lane * 4;
        float4 zv = *(const float4*)(z + base);
        float a0 = 0.f, a1 = 0.f;
        const float* zp = (const float*)&zv;
#pragma unroll
        for (int j = 0; j < 4; ++j) {
            float p = ((float)(base + j) + 0.5f) * (1.0f / 512.0f) - 0.5f;
            p = fminf(fmaxf(p, 0.0f), (float)(COARSE - 1));
            float f = p - floorf(p);
            a0 += zp[j] * (1.0f - f);
            a1 += zp[j] * f;
        }
#pragma unroll
        for (int off = 32; off >= 1; off >>= 1) {
            a0 += __shfl_xor(a0, off, 64);
            a1 += __shfl_xor(a1, off, 64);
        }
        if (lane == 0) M[chunk] = make_float2(a0, a1);
    } else {
        __shared__ unsigned hc[NB], hr[NB];
        int blk = b - 2048;
        if (t < 256) { hc[t] = 0u; hr[t] = 0u; }
        __syncthreads();
        int base = blk * EPB;
#pragma unroll
        for (int it = 0; it < 4; ++it) {
            int e = base + it * 2048 + t * 4;
            v4i r = __builtin_nontemporal_load((const v4i*)(rows + e));
            v4i c = __builtin_nontemporal_load((const v4i*)(cols + e));
            atomicAdd(&hr[r.x >> 14], 1u); atomicAdd(&hr[r.y >> 14], 1u);
            atomicAdd(&hr[r.z >> 14], 1u); atomicAdd(&hr[r.w >> 14], 1u);
            atomicAdd(&hc[c.x >> 14], 1u); atomicAdd(&hc[c.y >> 14], 1u);
            atomicAdd(&hc[c.z >> 14], 1u); atomicAdd(&hc[c.w >> 14], 1u);
        }
        __syncthreads();
        if (t < 256) {
            colBO[t * HB + blk] = hc[t];
            rowBC[t * HB + blk] = hr[t];
        }
    }
}

// ============ kB: level sums (0..79) + col per-bucket scan (80..335) + row totals (336..591)
__global__ __launch_bounds__(256) void kB(const float2* __restrict__ M,
                                          const float* __restrict__ V,
                                          float* __restrict__ S,
                                          unsigned* __restrict__ colBO,
                                          unsigned* __restrict__ colTotal,
                                          const unsigned* __restrict__ rowBC,
                                          unsigned* __restrict__ rowTotal) {
    int b = blockIdx.x, t = threadIdx.x;
    if (b < 80) {
        int lvl = b >> 3, slice = b & 7;
        const float2* Vl = (const float2*)(V + lvl * COARSE * 2);
        float s0 = 0.f, s1 = 0.f;
        int c0 = slice * 2048 + t * 8;
#pragma unroll
        for (int cc = 0; cc < 8; ++cc) {
            int c = c0 + cc;
            float2 m = M[c];
            int k = (c > 0) ? ((c - 1) >> 1) : 0;
            int kp = min(k + 1, COARSE - 1);
            float2 vk = Vl[k], vkp = Vl[kp];
            s0 += vk.x * m.x + vkp.x * m.y;
            s1 += vk.y * m.x + vkp.y * m.y;
        }
        int gw = min(1 << (10 - lvl), 64);
        for (int sh = gw >> 1; sh >= 1; sh >>= 1) {
            s0 += __shfl_xor(s0, sh, 64);
            s1 += __shfl_xor(s1, sh, 64);
        }
        if ((t & (gw - 1)) == 0) {
            int bb = c0 >> (13 - lvl);
            int soff = (2 << lvl) - 2;
            unsafeAtomicAdd(&S[(soff + bb) * 2 + 0], s0);
            unsafeAtomicAdd(&S[(soff + bb) * 2 + 1], s1);
        }
    } else if (b < 336) {
        int bb = b - 80;
        __shared__ unsigned wsum[4], wbase[4];
        unsigned* p = colBO + bb * HB;
        v4u a = ((const v4u*)p)[t];
        unsigned s = a.x + a.y + a.z + a.w;
        unsigned incl = s;
#pragma unroll
        for (int off = 1; off < 64; off <<= 1) {
            unsigned n = __shfl_up(incl, off, 64);
            if ((t & 63) >= off) incl += n;
        }
        if ((t & 63) == 63) wsum[t >> 6] = incl;
        __syncthreads();
        if (t == 0) {
            unsigned acc = 0;
            for (int i = 0; i < 4; ++i) { wbase[i] = acc; acc += wsum[i]; }
            colTotal[bb] = acc;
        }
        __syncthreads();
        unsigned excl = wbase[t >> 6] + incl - s;
        v4u e;
        e.x = excl; e.y = excl + a.x; e.z = e.y + a.y; e.w = e.z + a.z;
        ((v4u*)p)[t] = e;
    } else {
        int bb = b - 336;
        __shared__ unsigned red[4];
        v4u vv = ((const v4u*)(rowBC + bb * HB))[t];
        unsigned s = vv.x + vv.y + vv.z + vv.w;
#pragma unroll
        for (int off = 32; off >= 1; off >>= 1) s += __shfl_xor(s, off, 64);
        if ((t & 63) == 0) red[t >> 6] = s;
        __syncthreads();
        if (t == 0) rowTotal[bb] = red[0] + red[1] + red[2] + red[3];
    }
}

// ============ kC: w=diag*z+lowrank->bf16 (0..2047) + col-binning (2048..3071) + rowCtr init (3072)
// Binning now sub-tiled (2 x 4096) with bucket id packed into entry spare bits:
// LDS ~36 KiB -> 4 blocks/CU (was 76 KiB -> 2).
__global__ __launch_bounds__(512) void kC(const float* __restrict__ diag,
                                          const float* __restrict__ z,
                                          const float* __restrict__ S,
                                          const float* __restrict__ U,
                                          unsigned short* __restrict__ wb,
                                          const int* __restrict__ rows,
                                          const int* __restrict__ cols,
                                          const float* __restrict__ vals,
                                          const unsigned* __restrict__ colBO,
                                          const unsigned* __restrict__ colTotal,
                                          v2u* __restrict__ colBinned,
                                          const unsigned* __restrict__ rowTotal,
                                          unsigned* __restrict__ rowCtr) {
    int b = blockIdx.x, t = threadIdx.x;
    if (b < 2048) {
        int tid = b * 512 + t;
        int base = tid * 4;
        int c = base >> 8;                // wave-uniform chunk
        int k = (c > 0) ? ((c - 1) >> 1) : 0;
        int kp = min(k + 1, COARSE - 1);
        float g0 = 0.f, g1 = 0.f;
#pragma unroll
        for (int lvl = 0; lvl < LEVELS; ++lvl) {
            int sib = (c >> (13 - lvl)) ^ 1;
            int soff = (2 << lvl) - 2;
            float2 s2 = ((const float2*)S)[soff + sib];
            const float2* Ul = (const float2*)(U + lvl * COARSE * 2);
            float2 uk = Ul[k], ukp = Ul[kp];
            g0 += uk.x * s2.x + uk.y * s2.y;
            g1 += ukp.x * s2.x + ukp.y * s2.y;
        }
        float4 d4 = *(const float4*)(diag + base);
        float4 z4 = *(const float4*)(z + base);
        const float* dp = (const float*)&d4;
        const float* zp = (const float*)&z4;
        ushort4 h4;
        unsigned short* hp = (unsigned short*)&h4;
#pragma unroll
        for (int j = 0; j < 4; ++j) {
            float p = ((float)(base + j) + 0.5f) * (1.0f / 512.0f) - 0.5f;
            p = fminf(fmaxf(p, 0.0f), (float)(COARSE - 1));
            float f = p - floorf(p);
            hp[j] = f2bf(dp[j] * zp[j] + (g0 + f * (g1 - g0)));
        }
        *(ushort4*)(wb + base) = h4;
    } else if (b < 3072) {
        __shared__ v2u sortedP[CSUB];          // 32 KiB
        __shared__ unsigned cur[NB], gb[NB], run[NB];
        __shared__ unsigned wsum[4], wbase[4];
        int blk = b - 2048;
        int base = blk * EPB;
        // global segment base per col bucket: scan colTotal; init running offsets
        unsigned tv = (t < 256) ? colTotal[t] : 0u;
        unsigned incl = tv;
        if (t < 256) {
#pragma unroll
            for (int off = 1; off < 64; off <<= 1) {
                unsigned n = __shfl_up(incl, off, 64);
                if ((t & 63) >= off) incl += n;
            }
            if ((t & 63) == 63) wsum[t >> 6] = incl;
            run[t] = colBO[t * HB + blk];
        }
        __syncthreads();
        if (t == 0) {
            unsigned a = 0;
            for (int i = 0; i < 4; ++i) { wbase[i] = a; a += wsum[i]; }
        }
        __syncthreads();
        unsigned segBase = (t < 256) ? (wbase[t >> 6] + incl - tv) : 0u;

#pragma unroll 1
        for (int s = 0; s < EPB / CSUB; ++s) {
            int sbase = base + s * CSUB;
            v4i r[2], c[2];
            v4f v[2];
#pragma unroll
            for (int j = 0; j < 2; ++j) {
                int e = sbase + j * 2048 + t * 4;
                r[j] = __builtin_nontemporal_load((const v4i*)(rows + e));
                c[j] = __builtin_nontemporal_load((const v4i*)(cols + e));
                v[j] = __builtin_nontemporal_load((const v4f*)(vals + e));
            }
            if (t < 256) cur[t] = 0u;
            __syncthreads();
            // local histogram by col bucket
#pragma unroll
            for (int j = 0; j < 2; ++j) {
                atomicAdd(&cur[c[j].x >> 14], 1u);
                atomicAdd(&cur[c[j].y >> 14], 1u);
                atomicAdd(&cur[c[j].z >> 14], 1u);
                atomicAdd(&cur[c[j].w >> 14], 1u);
            }
            __syncthreads();
            // scan local hist
            unsigned lv = (t < 256) ? cur[t] : 0u;
            unsigned lincl = lv;
            if (t < 256) {
#pragma unroll
                for (int off = 1; off < 64; off <<= 1) {
                    unsigned n = __shfl_up(lincl, off, 64);
                    if ((t & 63) >= off) lincl += n;
                }
                if ((t & 63) == 63) wsum[t >> 6] = lincl;
            }
            __syncthreads();
            if (t == 0) {
                unsigned a = 0;
                for (int i = 0; i < 4; ++i) { wbase[i] = a; a += wsum[i]; }
            }
            __syncthreads();
            if (t < 256) {
                unsigned lexcl = wbase[t >> 6] + lincl - lv;
                gb[t] = segBase + run[t] - lexcl;
                cur[t] = lexcl;
                run[t] += lv;
            }
            __syncthreads();
            // place, sorted by col bucket; bucket id packed into ent.y bits [4:11]
#pragma unroll
            for (int j = 0; j < 2; ++j) {
                const int* rp = (const int*)&r[j];
                const int* cp = (const int*)&c[j];
                const float* vp = (const float*)&v[j];
#pragma unroll
                for (int kk = 0; kk < 4; ++kk) {
                    int row = rp[kk], col = cp[kk];
                    unsigned cb = (unsigned)col >> 14;
                    unsigned cl = (unsigned)col & 16383u;
                    v2u ent;
                    ent.x = (unsigned)row | ((cl & 0x3FFu) << 22);
                    ent.y = (cl >> 10) | (cb << 4) | ((unsigned)f2bf(vp[kk]) << 16);
                    unsigned i = atomicAdd(&cur[cb], 1u);
                    sortedP[i] = ent;
                }
            }
            __syncthreads();
            // coalesced write-out (bucket recovered from packed bits; kD ignores them)
#pragma unroll
            for (int k = 0; k < CSUB / 512; ++k) {
                int i = k * 512 + t;
                v2u e = sortedP[i];
                unsigned bkt = (e.y >> 4) & 0xFFu;
                __builtin_nontemporal_store(e, colBinned + gb[bkt] + i);
            }
            __syncthreads();
        }
    } else {
        // rowCtr init: exclusive scan of rowTotal
        __shared__ unsigned wsum[4], wbase[4];
        unsigned tv = (t < 256) ? rowTotal[t] : 0u;
        unsigned incl = tv;
        if (t < 256) {
#pragma unroll
            for (int off = 1; off < 64; off <<= 1) {
                unsigned n = __shfl_up(incl, off, 64);
                if ((t & 63) >= off) incl += n;
            }
            if ((t & 63) == 63) wsum[t >> 6] = incl;
        }
        __syncthreads();
        if (t == 0) {
            unsigned a = 0;
            for (int i = 0; i < 4; ++i) { wbase[i] = a; a += wsum[i]; }
        }
        __syncthreads();
        if (t < 256) rowCtr[t] = wbase[t >> 6] + incl - tv;
    }
}

// ============ kD: per col-bucket — products via LDS w-slice, LDS-sorted row-bucket scatter
// Grid = 2*NB: each col-bucket is split across 2 blocks taking alternating 4096-entry
// tiles (rowCtr reservation is already a global atomic, so ordering is free).
// LDS ~54 KiB -> 2 blocks/CU (was 74 KiB + grid 256 -> 1 block/CU).
__global__ __launch_bounds__(512) void kD(const unsigned short* __restrict__ wb,
                                          const v2u* __restrict__ colBinned,
                                          const unsigned* __restrict__ colTotal,
                                          unsigned* __restrict__ rowCtr,
                                          unsigned* __restrict__ packed) {
    __shared__ unsigned short wSl[CB_SZ];     // 32 KiB
    __shared__ unsigned sortedP[TILE_D];      // 16 KiB
    __shared__ unsigned char sortedB[TILE_D]; // 4 KiB
    __shared__ unsigned cur[NB], gb[NB];
    __shared__ unsigned wsum[4], wbase[4];
    __shared__ unsigned sS;
    int b = blockIdx.x >> 1, h = blockIdx.x & 1, t = threadIdx.x;

    // segment base: scan colTotal
    unsigned tv = (t < 256) ? colTotal[t] : 0u;
    unsigned incl = tv;
    if (t < 256) {
#pragma unroll
        for (int off = 1; off < 64; off <<= 1) {
            unsigned n = __shfl_up(incl, off, 64);
            if ((t & 63) >= off) incl += n;
        }
        if ((t & 63) == 63) wsum[t >> 6] = incl;
    }
    __syncthreads();
    if (t == 0) {
        unsigned a = 0;
        for (int i = 0; i < 4; ++i) { wbase[i] = a; a += wsum[i]; }
    }
    __syncthreads();
    if (t < 256 && t == b) sS = wbase[t >> 6] + incl - tv;
    // load w slice (bf16) into LDS
    const v4u* wg = (const v4u*)(wb + (size_t)b * CB_SZ);
    for (int i = t; i < CB_SZ / 8; i += 512) ((v4u*)wSl)[i] = wg[i];
    __syncthreads();
    unsigned s0 = sS, n = colTotal[b];

    for (unsigned t0 = (unsigned)h * TILE_D; t0 < n; t0 += 2 * TILE_D) {
        unsigned cnt = min((unsigned)TILE_D, n - t0);
        v2u ev[TILE_D / 512];
#pragma unroll
        for (int k = 0; k < TILE_D / 512; ++k) {
            unsigned i = (unsigned)(k * 512 + t);
            if (i < cnt) ev[k] = __builtin_nontemporal_load(colBinned + s0 + t0 + i);
        }
        if (t < 256) cur[t] = 0u;
        __syncthreads();
#pragma unroll
        for (int k = 0; k < TILE_D / 512; ++k) {
            if ((unsigned)(k * 512 + t) < cnt)
                atomicAdd(&cur[(ev[k].x & 0x3FFFFFu) >> 14], 1u);
        }
        __syncthreads();
        unsigned lv = (t < 256) ? cur[t] : 0u;
        unsigned lincl = lv;
        if (t < 256) {
#pragma unroll
            for (int off = 1; off < 64; off <<= 1) {
                unsigned nn = __shfl_up(lincl, off, 64);
                if ((t & 63) >= off) lincl += nn;
            }
            if ((t & 63) == 63) wsum[t >> 6] = lincl;
        }
        __syncthreads();
        if (t == 0) {
            unsigned a = 0;
            for (int i = 0; i < 4; ++i) { wbase[i] = a; a += wsum[i]; }
        }
        __syncthreads();
        if (t < 256) {
            unsigned lexcl = wbase[t >> 6] + lincl - lv;
            gb[t] = atomicAdd(&rowCtr[t], lv) - lexcl;
            cur[t] = lexcl;
        }
        __syncthreads();
#pragma unroll
        for (int k = 0; k < TILE_D / 512; ++k) {
            if ((unsigned)(k * 512 + t) < cnt) {
                v2u e = ev[k];
                unsigned row = e.x & 0x3FFFFFu;
                unsigned cl = (e.x >> 22) | ((e.y & 0xFu) << 10);
                float p = bf2f((unsigned short)(e.y >> 16)) * bf2f(wSl[cl]);
                unsigned rb = row >> 14;
                unsigned i = atomicAdd(&cur[rb], 1u);
                sortedP[i] = ((row & 16383u) << 18) | f18(p);
                sortedB[i] = (unsigned char)rb;
            }
        }
        __syncthreads();
#pragma unroll
        for (int k = 0; k < TILE_D / 512; ++k) {
            unsigned i = (unsigned)(k * 512 + t);
            if (i < cnt) {
                unsigned bkt = sortedB[i];
                __builtin_nontemporal_store(sortedP[i], packed + gb[bkt] + i);
            }
        }
        __syncthreads();
    }
}

// ============ kE: per row-bucket LDS accumulate + fused loss
__global__ __launch_bounds__(1024) void kE(const unsigned* __restrict__ packed,
                                           const unsigned* __restrict__ rowTotal,
                                           const float* __restrict__ z,
                                           float* __restrict__ out) {
    __shared__ float acc[RB_SZ];          // 64 KiB
    __shared__ unsigned sb;
    __shared__ unsigned wsum[4], wbase[4];
    __shared__ float red[16];
    int b = blockIdx.x, t = threadIdx.x;

    unsigned tv = (t < 256) ? rowTotal[t] : 0u;
    unsigned incl = tv;
    if (t < 256) {
#pragma unroll
        for (int off = 1; off < 64; off <<= 1) {
            unsigned n = __shfl_up(incl, off, 64);
            if ((t & 63) >= off) incl += n;
        }
        if ((t & 63) == 63) wsum[t >> 6] = incl;
    }
    __syncthreads();
    if (t == 0) {
        unsigned a = 0;
        for (int i = 0; i < 4; ++i) { wbase[i] = a; a += wsum[i]; }
    }
    __syncthreads();
    if (t < 256 && t == b) sb = wbase[t >> 6] + incl - tv;
    for (int i = t; i < RB_SZ / 4; i += 1024) ((float4*)acc)[i] = make_float4(0.f, 0.f, 0.f, 0.f);
    __syncthreads();

    unsigned s0 = sb, n = rowTotal[b];
    for (unsigned i = t; i < n; i += 1024) {
        unsigned e = __builtin_nontemporal_load(packed + s0 + i);
        atomicAdd(&acc[e >> 18], __uint_as_float((e & 0x3FFFFu) << 14));
    }
    __syncthreads();

    float part = 0.f;
    int gbase = b * RB_SZ;
    for (int i = t; i < RB_SZ; i += 1024) {
        float d = acc[i] - z[gbase + i];
        part += d * d;
    }
#pragma unroll
    for (int off = 32; off >= 1; off >>= 1) part += __shfl_xor(part, off, 64);
    if ((t & 63) == 0) red[t >> 6] = part;
    __syncthreads();
    if (t == 0) {
        float s = 0.f;
        for (int i = 0; i < 16; ++i) s += red[i];
        unsafeAtomicAdd(out, s * (1.0f / (float)N_NODES));
    }
}

extern "C" void kernel_launch(void* const* d_in, const int* in_sizes, int n_in,
                              void* d_out, int out_size, void* d_ws, size_t ws_size,
                              hipStream_t stream) {
    const float* diag  = (const float*)d_in[0];
    const float* U     = (const float*)d_in[1];
    const float* V     = (const float*)d_in[2];
    const float* Avals = (const float*)d_in[3];
    const float* z     = (const float*)d_in[4];
    const int*   Aidx  = (const int*)d_in[5];
    const int* rows = Aidx;
    const int* cols = Aidx + NNZ_E;

    char* ws = (char*)d_ws;
    size_t off = 0;
    unsigned short* wb  = (unsigned short*)(ws + off); off += (size_t)N_NODES * 2;  // 8 MiB
    v2u* colBinned      = (v2u*)(ws + off);            off += (size_t)NNZ_E * 8;    // 64 MiB
    unsigned* packed    = (unsigned*)(ws + off);       off += (size_t)NNZ_E * 4;    // 32 MiB
    unsigned* colBO     = (unsigned*)(ws + off);       off += (size_t)NB * HB * 4;  // 1 MiB
    unsigned* rowBC     = (unsigned*)(ws + off);       off += (size_t)NB * HB * 4;  // 1 MiB
    unsigned* colTotal  = (unsigned*)(ws + off);       off += 1024;
    unsigned* rowTotal  = (unsigned*)(ws + off);       off += 1024;
    unsigned* rowCtr    = (unsigned*)(ws + off);       off += 1024;
    float2* M           = (float2*)(ws + off);         off += (size_t)NCHUNK * 8;   // 128 KiB
    float* S            = (float*)(ws + off);          off += 16384;

    kA<<<3072, 512, 0, stream>>>(z, M, S, (float*)d_out, rows, cols, colBO, rowBC);
    kB<<<592, 256, 0, stream>>>(M, V, S, colBO, colTotal, rowBC, rowTotal);
    kC<<<3073, 512, 0, stream>>>(diag, z, S, U, wb, rows, cols, Avals,
                                 colBO, colTotal, colBinned, rowTotal, rowCtr);
    kD<<<NB * 2, 512, 0, stream>>>(wb, colBinned, colTotal, rowCtr, packed);
    kE<<<NB, 1024, 0, stream>>>(packed, rowTotal, z, (float*)d_out);
}

// Round 2
// 297.720 us; speedup vs baseline: 1.1381x; 1.1381x over previous
//
#include <hip/hip_runtime.h>

#define N_NODES 4194304
#define LEVELS  10
#define COARSE  8192
#define NNZ_E   8388608
#define NB      256      // row buckets == col buckets
#define CB_SZ   16384    // cols per col-bucket (32 KiB bf16 LDS slice)
#define RB_SZ   16384    // rows per row-bucket (64 KiB LDS accumulator)
#define HB      1024     // binning blocks
#define EPB     8192     // edges per binning block
#define TILE    8192     // kD tile size
#define CAPC    34816u   // col-bucket segment capacity (mean 32768, +11 sigma)
#define CAPR    34816u   // row-bucket segment capacity

typedef int          v4i __attribute__((ext_vector_type(4)));
typedef float        v4f __attribute__((ext_vector_type(4)));
typedef unsigned int v4u __attribute__((ext_vector_type(4)));
typedef unsigned int v2u __attribute__((ext_vector_type(2)));

static __device__ __forceinline__ unsigned short f2bf(float x) {
    unsigned u = __float_as_uint(x);
    return (unsigned short)((u + 0x7FFFu + ((u >> 16) & 1u)) >> 16);
}
static __device__ __forceinline__ float bf2f(unsigned short h) {
    return __uint_as_float((unsigned)h << 16);
}
static __device__ __forceinline__ unsigned f18(float p) {   // 1s+8e+9m, RN
    return ((__float_as_uint(p) + 0x2000u) >> 14) & 0x3FFFFu;
}

// ============ kA: HODLR moments only (hist pass eliminated by fixed-capacity segments)
__global__ __launch_bounds__(512) void kA(const float* __restrict__ z,
                                          float2* __restrict__ M,
                                          float* __restrict__ S,
                                          float* __restrict__ out,
                                          unsigned* __restrict__ colCtr,
                                          unsigned* __restrict__ rowCtr) {
    int b = blockIdx.x, t = threadIdx.x;
    if (b == 0) {
        for (int i = t; i < 2046 * 2; i += 512) S[i] = 0.f;
        if (t == 0) out[0] = 0.f;
        if (t < 256) {
            colCtr[t] = (unsigned)t * CAPC;
            rowCtr[t] = (unsigned)t * CAPR;
        }
    }
    int lane = t & 63, wave = t >> 6;
    int chunk = b * 8 + wave;
    int base = chunk * 256 + lane * 4;
    float4 zv = *(const float4*)(z + base);
    float a0 = 0.f, a1 = 0.f;
    const float* zp = (const float*)&zv;
#pragma unroll
    for (int j = 0; j < 4; ++j) {
        float p = ((float)(base + j) + 0.5f) * (1.0f / 512.0f) - 0.5f;
        p = fminf(fmaxf(p, 0.0f), (float)(COARSE - 1));
        float f = p - floorf(p);
        a0 += zp[j] * (1.0f - f);
        a1 += zp[j] * f;
    }
#pragma unroll
    for (int off = 32; off >= 1; off >>= 1) {
        a0 += __shfl_xor(a0, off, 64);
        a1 += __shfl_xor(a1, off, 64);
    }
    if (lane == 0) M[chunk] = make_float2(a0, a1);
}

// ============ kB: level sums only (scan branches eliminated)
__global__ __launch_bounds__(256) void kB(const float2* __restrict__ M,
                                          const float* __restrict__ V,
                                          float* __restrict__ S) {
    int b = blockIdx.x, t = threadIdx.x;
    int lvl = b >> 3, slice = b & 7;
    const float2* Vl = (const float2*)(V + lvl * COARSE * 2);
    float s0 = 0.f, s1 = 0.f;
    int c0 = slice * 2048 + t * 8;
#pragma unroll
    for (int cc = 0; cc < 8; ++cc) {
        int c = c0 + cc;
        float2 m = M[c];
        int k = (c > 0) ? ((c - 1) >> 1) : 0;
        int kp = min(k + 1, COARSE - 1);
        float2 vk = Vl[k], vkp = Vl[kp];
        s0 += vk.x * m.x + vkp.x * m.y;
        s1 += vk.y * m.x + vkp.y * m.y;
    }
    int gw = min(1 << (10 - lvl), 64);
    for (int sh = gw >> 1; sh >= 1; sh >>= 1) {
        s0 += __shfl_xor(s0, sh, 64);
        s1 += __shfl_xor(s1, sh, 64);
    }
    if ((t & (gw - 1)) == 0) {
        int bb = c0 >> (13 - lvl);
        int soff = (2 << lvl) - 2;
        unsafeAtomicAdd(&S[(soff + bb) * 2 + 0], s0);
        unsafeAtomicAdd(&S[(soff + bb) * 2 + 1], s1);
    }
}

// ============ kC: w=diag*z+lowrank->bf16 (0..2047) + col-binning (2048..3071)
// Binning: full 8192-entry tile, loads hoisted upfront, bucket id packed in entry
// spare bits (no sortedB byte array). Segment base = bucket*CAPC + global atomic
// reservation (no precomputed histogram needed).
__global__ __launch_bounds__(512) void kC(const float* __restrict__ diag,
                                          const float* __restrict__ z,
                                          const float* __restrict__ S,
                                          const float* __restrict__ U,
                                          unsigned short* __restrict__ wb,
                                          const int* __restrict__ rows,
                                          const int* __restrict__ cols,
                                          const float* __restrict__ vals,
                                          unsigned* __restrict__ colCtr,
                                          v2u* __restrict__ colBinned) {
    int b = blockIdx.x, t = threadIdx.x;
    if (b < 2048) {
        int tid = b * 512 + t;
        int base = tid * 4;
        int c = base >> 8;                // wave-uniform chunk
        int k = (c > 0) ? ((c - 1) >> 1) : 0;
        int kp = min(k + 1, COARSE - 1);
        float g0 = 0.f, g1 = 0.f;
#pragma unroll
        for (int lvl = 0; lvl < LEVELS; ++lvl) {
            int sib = (c >> (13 - lvl)) ^ 1;
            int soff = (2 << lvl) - 2;
            float2 s2 = ((const float2*)S)[soff + sib];
            const float2* Ul = (const float2*)(U + lvl * COARSE * 2);
            float2 uk = Ul[k], ukp = Ul[kp];
            g0 += uk.x * s2.x + uk.y * s2.y;
            g1 += ukp.x * s2.x + ukp.y * s2.y;
        }
        float4 d4 = *(const float4*)(diag + base);
        float4 z4 = *(const float4*)(z + base);
        const float* dp = (const float*)&d4;
        const float* zp = (const float*)&z4;
        ushort4 h4;
        unsigned short* hp = (unsigned short*)&h4;
#pragma unroll
        for (int j = 0; j < 4; ++j) {
            float p = ((float)(base + j) + 0.5f) * (1.0f / 512.0f) - 0.5f;
            p = fminf(fmaxf(p, 0.0f), (float)(COARSE - 1));
            float f = p - floorf(p);
            hp[j] = f2bf(dp[j] * zp[j] + (g0 + f * (g1 - g0)));
        }
        *(ushort4*)(wb + base) = h4;
    } else {
        __shared__ v2u sortedP[EPB];           // 64 KiB
        __shared__ unsigned cur[NB], gb[NB];
        __shared__ unsigned wsum[4], wbase[4];
        int blk = b - 2048;
        int base = blk * EPB;
        // hoist all streaming loads upfront (latency overlapped with hist/scan)
        v4i r[4], c[4];
        v4f v[4];
#pragma unroll
        for (int j = 0; j < 4; ++j) {
            int e = base + j * 2048 + t * 4;
            r[j] = __builtin_nontemporal_load((const v4i*)(rows + e));
            c[j] = __builtin_nontemporal_load((const v4i*)(cols + e));
            v[j] = __builtin_nontemporal_load((const v4f*)(vals + e));
        }
        if (t < 256) cur[t] = 0u;
        __syncthreads();
        // local histogram by col bucket
#pragma unroll
        for (int j = 0; j < 4; ++j) {
            atomicAdd(&cur[c[j].x >> 14], 1u);
            atomicAdd(&cur[c[j].y >> 14], 1u);
            atomicAdd(&cur[c[j].z >> 14], 1u);
            atomicAdd(&cur[c[j].w >> 14], 1u);
        }
        __syncthreads();
        // scan local hist
        unsigned lv = (t < 256) ? cur[t] : 0u;
        unsigned lincl = lv;
        if (t < 256) {
#pragma unroll
            for (int off = 1; off < 64; off <<= 1) {
                unsigned n = __shfl_up(lincl, off, 64);
                if ((t & 63) >= off) lincl += n;
            }
            if ((t & 63) == 63) wsum[t >> 6] = lincl;
        }
        __syncthreads();
        if (t == 0) {
            unsigned a = 0;
            for (int i = 0; i < 4; ++i) { wbase[i] = a; a += wsum[i]; }
        }
        __syncthreads();
        if (t < 256) {
            unsigned lexcl = wbase[t >> 6] + lincl - lv;
            gb[t] = atomicAdd(&colCtr[t], lv) - lexcl;   // global reservation
            cur[t] = lexcl;
        }
        __syncthreads();
        // place, sorted by col bucket; bucket id packed into ent.y bits [4:11]
#pragma unroll
        for (int j = 0; j < 4; ++j) {
            const int* rp = (const int*)&r[j];
            const int* cp = (const int*)&c[j];
            const float* vp = (const float*)&v[j];
#pragma unroll
            for (int kk = 0; kk < 4; ++kk) {
                int row = rp[kk], col = cp[kk];
                unsigned cb = (unsigned)col >> 14;
                unsigned cl = (unsigned)col & 16383u;
                v2u ent;
                ent.x = (unsigned)row | ((cl & 0x3FFu) << 22);
                ent.y = (cl >> 10) | (cb << 4) | ((unsigned)f2bf(vp[kk]) << 16);
                unsigned i = atomicAdd(&cur[cb], 1u);
                sortedP[i] = ent;
            }
        }
        __syncthreads();
        // coalesced write-out (bucket recovered from packed bits; kD ignores them)
#pragma unroll
        for (int k = 0; k < 16; ++k) {
            int i = k * 512 + t;
            v2u e = sortedP[i];
            unsigned bkt = (e.y >> 4) & 0xFFu;
            __builtin_nontemporal_store(e, colBinned + gb[bkt] + i);
        }
    }
}

// ============ kD: per col-bucket — products via LDS w-slice, LDS-sorted row-bucket scatter
// Grid 2*NB: bucket pair-split over alternating FULL 8192-entry tiles
// (2 blocks/CU, write runs stay 32-entry avg). Segment base = b*CAPC, count from colCtr.
__global__ __launch_bounds__(512) void kD(const unsigned short* __restrict__ wb,
                                          const v2u* __restrict__ colBinned,
                                          const unsigned* __restrict__ colCtr,
                                          unsigned* __restrict__ rowCtr,
                                          unsigned* __restrict__ packed) {
    __shared__ unsigned short wSl[CB_SZ];   // 32 KiB
    __shared__ unsigned sortedP[TILE];      // 32 KiB
    __shared__ unsigned char sortedB[TILE]; // 8 KiB
    __shared__ unsigned cur[NB], gb[NB];
    __shared__ unsigned wsum[4], wbase[4];
    int b = blockIdx.x >> 1, h = blockIdx.x & 1, t = threadIdx.x;

    unsigned s0 = (unsigned)b * CAPC;
    unsigned n = colCtr[b] - s0;
    // load w slice (bf16) into LDS
    const v4u* wg = (const v4u*)(wb + (size_t)b * CB_SZ);
    for (int i = t; i < CB_SZ / 8; i += 512) ((v4u*)wSl)[i] = wg[i];
    __syncthreads();

    for (unsigned t0 = (unsigned)h * TILE; t0 < n; t0 += 2u * TILE) {
        unsigned cnt = min((unsigned)TILE, n - t0);
        v2u ev[16];
#pragma unroll
        for (int k = 0; k < 16; ++k) {
            unsigned i = (unsigned)(k * 512 + t);
            if (i < cnt) ev[k] = __builtin_nontemporal_load(colBinned + s0 + t0 + i);
        }
        if (t < 256) cur[t] = 0u;
        __syncthreads();
#pragma unroll
        for (int k = 0; k < 16; ++k) {
            if ((unsigned)(k * 512 + t) < cnt)
                atomicAdd(&cur[(ev[k].x & 0x3FFFFFu) >> 14], 1u);
        }
        __syncthreads();
        unsigned lv = (t < 256) ? cur[t] : 0u;
        unsigned lincl = lv;
        if (t < 256) {
#pragma unroll
            for (int off = 1; off < 64; off <<= 1) {
                unsigned nn = __shfl_up(lincl, off, 64);
                if ((t & 63) >= off) lincl += nn;
            }
            if ((t & 63) == 63) wsum[t >> 6] = lincl;
        }
        __syncthreads();
        if (t == 0) {
            unsigned a = 0;
            for (int i = 0; i < 4; ++i) { wbase[i] = a; a += wsum[i]; }
        }
        __syncthreads();
        if (t < 256) {
            unsigned lexcl = wbase[t >> 6] + lincl - lv;
            gb[t] = atomicAdd(&rowCtr[t], lv) - lexcl;
            cur[t] = lexcl;
        }
        __syncthreads();
#pragma unroll
        for (int k = 0; k < 16; ++k) {
            if ((unsigned)(k * 512 + t) < cnt) {
                v2u e = ev[k];
                unsigned row = e.x & 0x3FFFFFu;
                unsigned cl = (e.x >> 22) | ((e.y & 0xFu) << 10);
                float p = bf2f((unsigned short)(e.y >> 16)) * bf2f(wSl[cl]);
                unsigned rb = row >> 14;
                unsigned i = atomicAdd(&cur[rb], 1u);
                sortedP[i] = ((row & 16383u) << 18) | f18(p);
                sortedB[i] = (unsigned char)rb;
            }
        }
        __syncthreads();
#pragma unroll
        for (int k = 0; k < 16; ++k) {
            unsigned i = (unsigned)(k * 512 + t);
            if (i < cnt) {
                unsigned bkt = sortedB[i];
                __builtin_nontemporal_store(sortedP[i], packed + gb[bkt] + i);
            }
        }
        __syncthreads();
    }
}

// ============ kE: per row-bucket LDS accumulate + fused loss (scan eliminated)
__global__ __launch_bounds__(1024) void kE(const unsigned* __restrict__ packed,
                                           const unsigned* __restrict__ rowCtr,
                                           const float* __restrict__ z,
                                           float* __restrict__ out) {
    __shared__ float acc[RB_SZ];          // 64 KiB
    __shared__ float red[16];
    int b = blockIdx.x, t = threadIdx.x;

    unsigned s0 = (unsigned)b * CAPR;
    unsigned n = rowCtr[b] - s0;
    for (int i = t; i < RB_SZ / 4; i += 1024) ((float4*)acc)[i] = make_float4(0.f, 0.f, 0.f, 0.f);
    __syncthreads();

    for (unsigned i = t; i < n; i += 1024) {
        unsigned e = __builtin_nontemporal_load(packed + s0 + i);
        atomicAdd(&acc[e >> 18], __uint_as_float((e & 0x3FFFFu) << 14));
    }
    __syncthreads();

    float part = 0.f;
    int gbase = b * RB_SZ;
    for (int i = t; i < RB_SZ; i += 1024) {
        float d = acc[i] - z[gbase + i];
        part += d * d;
    }
#pragma unroll
    for (int off = 32; off >= 1; off >>= 1) part += __shfl_xor(part, off, 64);
    if ((t & 63) == 0) red[t >> 6] = part;
    __syncthreads();
    if (t == 0) {
        float s = 0.f;
        for (int i = 0; i < 16; ++i) s += red[i];
        unsafeAtomicAdd(out, s * (1.0f / (float)N_NODES));
    }
}

extern "C" void kernel_launch(void* const* d_in, const int* in_sizes, int n_in,
                              void* d_out, int out_size, void* d_ws, size_t ws_size,
                              hipStream_t stream) {
    const float* diag  = (const float*)d_in[0];
    const float* U     = (const float*)d_in[1];
    const float* V     = (const float*)d_in[2];
    const float* Avals = (const float*)d_in[3];
    const float* z     = (const float*)d_in[4];
    const int*   Aidx  = (const int*)d_in[5];
    const int* rows = Aidx;
    const int* cols = Aidx + NNZ_E;

    char* ws = (char*)d_ws;
    size_t off = 0;
    unsigned short* wb  = (unsigned short*)(ws + off); off += (size_t)N_NODES * 2;       // 8 MiB
    v2u* colBinned      = (v2u*)(ws + off);            off += (size_t)NB * CAPC * 8;     // 68 MiB
    unsigned* packed    = (unsigned*)(ws + off);       off += (size_t)NB * CAPR * 4;     // 34 MiB
    unsigned* colCtr    = (unsigned*)(ws + off);       off += 1024;
    unsigned* rowCtr    = (unsigned*)(ws + off);       off += 1024;
    float2* M           = (float2*)(ws + off);         off += (size_t)(N_NODES / 256) * 8; // 128 KiB
    float* S            = (float*)(ws + off);          off += 16384;

    kA<<<2048, 512, 0, stream>>>(z, M, S, (float*)d_out, colCtr, rowCtr);
    kB<<<80, 256, 0, stream>>>(M, V, S);
    kC<<<3072, 512, 0, stream>>>(diag, z, S, U, wb, rows, cols, Avals, colCtr, colBinned);
    kD<<<NB * 2, 512, 0, stream>>>(wb, colBinned, colCtr, rowCtr, packed);
    kE<<<NB, 1024, 0, stream>>>(packed, rowCtr, z, (float*)d_out);
}

// Round 3
// 294.909 us; speedup vs baseline: 1.1489x; 1.0095x over previous
//
#include <hip/hip_runtime.h>

#define N_NODES 4194304
#define LEVELS  10
#define COARSE  8192
#define NNZ_E   8388608
#define NB      256      // row buckets
#define RB_SZ   16384    // rows per row-bucket (64 KiB LDS accumulator)
#define EPB     8192     // edges per binning block
#define CAPR    34816u   // row-bucket segment capacity (mean 32768, +11 sigma)

typedef int          v4i __attribute__((ext_vector_type(4)));
typedef float        v4f __attribute__((ext_vector_type(4)));
typedef unsigned int v4u __attribute__((ext_vector_type(4)));
typedef unsigned int v2u __attribute__((ext_vector_type(2)));

static __device__ __forceinline__ unsigned short f2bf(float x) {
    unsigned u = __float_as_uint(x);
    return (unsigned short)((u + 0x7FFFu + ((u >> 16) & 1u)) >> 16);
}
static __device__ __forceinline__ float bf2f(unsigned short h) {
    return __uint_as_float((unsigned)h << 16);
}

// ============ kA: HODLR moments (blocks 0..2047) + ROW-binning (2048..3071)
// Entry: x = col(22) | rowLocal[0:9]<<22 ; y = rowLocal[10:13] | rb<<4 | bf16(val)<<16
__global__ __launch_bounds__(512) void kA(const float* __restrict__ z,
                                          float2* __restrict__ M,
                                          float* __restrict__ S,
                                          float* __restrict__ out,
                                          const int* __restrict__ rows,
                                          const int* __restrict__ cols,
                                          const float* __restrict__ vals,
                                          unsigned* __restrict__ rowCtr,
                                          v2u* __restrict__ rowBinned) {
    int b = blockIdx.x, t = threadIdx.x;
    if (b < 2048) {
        if (b == 0) {
            for (int i = t; i < 2046 * 2; i += 512) S[i] = 0.f;
            if (t == 0) out[0] = 0.f;
        }
        int lane = t & 63, wave = t >> 6;
        int chunk = b * 8 + wave;
        int base = chunk * 256 + lane * 4;
        float4 zv = *(const float4*)(z + base);
        float a0 = 0.f, a1 = 0.f;
        const float* zp = (const float*)&zv;
#pragma unroll
        for (int j = 0; j < 4; ++j) {
            float p = ((float)(base + j) + 0.5f) * (1.0f / 512.0f) - 0.5f;
            p = fminf(fmaxf(p, 0.0f), (float)(COARSE - 1));
            float f = p - floorf(p);
            a0 += zp[j] * (1.0f - f);
            a1 += zp[j] * f;
        }
#pragma unroll
        for (int off = 32; off >= 1; off >>= 1) {
            a0 += __shfl_xor(a0, off, 64);
            a1 += __shfl_xor(a1, off, 64);
        }
        if (lane == 0) M[chunk] = make_float2(a0, a1);
    } else {
        __shared__ v2u sortedP[EPB];           // 64 KiB
        __shared__ unsigned cur[NB], gb[NB];
        __shared__ unsigned wsum[4], wbase[4];
        int blk = b - 2048;
        int base = blk * EPB;
        // hoist all streaming loads upfront
        v4i r[4], c[4];
        v4f v[4];
#pragma unroll
        for (int j = 0; j < 4; ++j) {
            int e = base + j * 2048 + t * 4;
            r[j] = __builtin_nontemporal_load((const v4i*)(rows + e));
            c[j] = __builtin_nontemporal_load((const v4i*)(cols + e));
            v[j] = __builtin_nontemporal_load((const v4f*)(vals + e));
        }
        if (t < 256) cur[t] = 0u;
        __syncthreads();
        // local histogram by row bucket
#pragma unroll
        for (int j = 0; j < 4; ++j) {
            atomicAdd(&cur[(unsigned)r[j].x >> 14], 1u);
            atomicAdd(&cur[(unsigned)r[j].y >> 14], 1u);
            atomicAdd(&cur[(unsigned)r[j].z >> 14], 1u);
            atomicAdd(&cur[(unsigned)r[j].w >> 14], 1u);
        }
        __syncthreads();
        // scan local hist
        unsigned lv = (t < 256) ? cur[t] : 0u;
        unsigned lincl = lv;
        if (t < 256) {
#pragma unroll
            for (int off = 1; off < 64; off <<= 1) {
                unsigned n = __shfl_up(lincl, off, 64);
                if ((t & 63) >= off) lincl += n;
            }
            if ((t & 63) == 63) wsum[t >> 6] = lincl;
        }
        __syncthreads();
        if (t == 0) {
            unsigned a = 0;
            for (int i = 0; i < 4; ++i) { wbase[i] = a; a += wsum[i]; }
        }
        __syncthreads();
        if (t < 256) {
            unsigned lexcl = wbase[t >> 6] + lincl - lv;
            gb[t] = (unsigned)t * CAPR + atomicAdd(&rowCtr[t], lv) - lexcl;
            cur[t] = lexcl;
        }
        __syncthreads();
        // place, sorted by row bucket; bucket id packed into ent.y bits [4:11]
#pragma unroll
        for (int j = 0; j < 4; ++j) {
            const int* rp = (const int*)&r[j];
            const int* cp = (const int*)&c[j];
            const float* vp = (const float*)&v[j];
#pragma unroll
            for (int kk = 0; kk < 4; ++kk) {
                unsigned row = (unsigned)rp[kk], col = (unsigned)cp[kk];
                unsigned rb = row >> 14;
                unsigned rl = row & 16383u;
                v2u ent;
                ent.x = col | ((rl & 0x3FFu) << 22);
                ent.y = (rl >> 10) | (rb << 4) | ((unsigned)f2bf(vp[kk]) << 16);
                unsigned i = atomicAdd(&cur[rb], 1u);
                sortedP[i] = ent;
            }
        }
        __syncthreads();
        // coalesced write-out (bucket recovered from packed bits; kE ignores them)
#pragma unroll
        for (int k = 0; k < 16; ++k) {
            int i = k * 512 + t;
            v2u e = sortedP[i];
            unsigned bkt = (e.y >> 4) & 0xFFu;
            __builtin_nontemporal_store(e, rowBinned + gb[bkt] + i);
        }
    }
}

// ============ kB: level sums
__global__ __launch_bounds__(256) void kB(const float2* __restrict__ M,
                                          const float* __restrict__ V,
                                          float* __restrict__ S) {
    int b = blockIdx.x, t = threadIdx.x;
    int lvl = b >> 3, slice = b & 7;
    const float2* Vl = (const float2*)(V + lvl * COARSE * 2);
    float s0 = 0.f, s1 = 0.f;
    int c0 = slice * 2048 + t * 8;
#pragma unroll
    for (int cc = 0; cc < 8; ++cc) {
        int c = c0 + cc;
        float2 m = M[c];
        int k = (c > 0) ? ((c - 1) >> 1) : 0;
        int kp = min(k + 1, COARSE - 1);
        float2 vk = Vl[k], vkp = Vl[kp];
        s0 += vk.x * m.x + vkp.x * m.y;
        s1 += vk.y * m.x + vkp.y * m.y;
    }
    int gw = min(1 << (10 - lvl), 64);
    for (int sh = gw >> 1; sh >= 1; sh >>= 1) {
        s0 += __shfl_xor(s0, sh, 64);
        s1 += __shfl_xor(s1, sh, 64);
    }
    if ((t & (gw - 1)) == 0) {
        int bb = c0 >> (13 - lvl);
        int soff = (2 << lvl) - 2;
        unsafeAtomicAdd(&S[(soff + bb) * 2 + 0], s0);
        unsafeAtomicAdd(&S[(soff + bb) * 2 + 1], s1);
    }
}

// ============ kCw: w = diag*z + lowrank -> bf16  (no LDS -> full occupancy)
__global__ __launch_bounds__(512) void kCw(const float* __restrict__ diag,
                                           const float* __restrict__ z,
                                           const float* __restrict__ S,
                                           const float* __restrict__ U,
                                           unsigned short* __restrict__ wb) {
    int b = blockIdx.x, t = threadIdx.x;
    int tid = b * 512 + t;
    int base = tid * 4;
    int c = base >> 8;                // wave-uniform chunk
    int k = (c > 0) ? ((c - 1) >> 1) : 0;
    int kp = min(k + 1, COARSE - 1);
    float g0 = 0.f, g1 = 0.f;
#pragma unroll
    for (int lvl = 0; lvl < LEVELS; ++lvl) {
        int sib = (c >> (13 - lvl)) ^ 1;
        int soff = (2 << lvl) - 2;
        float2 s2 = ((const float2*)S)[soff + sib];
        const float2* Ul = (const float2*)(U + lvl * COARSE * 2);
        float2 uk = Ul[k], ukp = Ul[kp];
        g0 += uk.x * s2.x + uk.y * s2.y;
        g1 += ukp.x * s2.x + ukp.y * s2.y;
    }
    float4 d4 = *(const float4*)(diag + base);
    float4 z4 = *(const float4*)(z + base);
    const float* dp = (const float*)&d4;
    const float* zp = (const float*)&z4;
    ushort4 h4;
    unsigned short* hp = (unsigned short*)&h4;
#pragma unroll
    for (int j = 0; j < 4; ++j) {
        float p = ((float)(base + j) + 0.5f) * (1.0f / 512.0f) - 0.5f;
        p = fminf(fmaxf(p, 0.0f), (float)(COARSE - 1));
        float f = p - floorf(p);
        hp[j] = f2bf(dp[j] * zp[j] + (g0 + f * (g1 - g0)));
    }
    *(ushort4*)(wb + base) = h4;
}

// ============ kE: per row-bucket — stream entries, gather wb[col] (LLC-resident),
// fp32 product, LDS accumulate, fused loss
__global__ __launch_bounds__(1024) void kE(const v2u* __restrict__ rowBinned,
                                           const unsigned* __restrict__ rowCtr,
                                           const unsigned short* __restrict__ wb,
                                           const float* __restrict__ z,
                                           float* __restrict__ out) {
    __shared__ float acc[RB_SZ];          // 64 KiB
    __shared__ float red[16];
    int b = blockIdx.x, t = threadIdx.x;

    unsigned n = rowCtr[b];
    const v2u* seg = rowBinned + (size_t)b * CAPR;
    for (int i = t; i < RB_SZ / 4; i += 1024) ((float4*)acc)[i] = make_float4(0.f, 0.f, 0.f, 0.f);
    __syncthreads();

    unsigned i = t;
    // 8-deep batches: keep 8 entry loads + 8 gathers in flight per thread
    for (; i + 7u * 1024u < n; i += 8u * 1024u) {
        v2u ev[8];
#pragma unroll
        for (int k = 0; k < 8; ++k)
            ev[k] = __builtin_nontemporal_load(seg + i + (unsigned)k * 1024u);
        unsigned short wv[8];
#pragma unroll
        for (int k = 0; k < 8; ++k)
            wv[k] = wb[ev[k].x & 0x3FFFFFu];
#pragma unroll
        for (int k = 0; k < 8; ++k) {
            unsigned rl = (ev[k].x >> 22) | ((ev[k].y & 0xFu) << 10);
            float p = bf2f((unsigned short)(ev[k].y >> 16)) * bf2f(wv[k]);
            atomicAdd(&acc[rl], p);
        }
    }
    for (; i < n; i += 1024u) {
        v2u e = __builtin_nontemporal_load(seg + i);
        unsigned rl = (e.x >> 22) | ((e.y & 0xFu) << 10);
        float p = bf2f((unsigned short)(e.y >> 16)) * bf2f(wb[e.x & 0x3FFFFFu]);
        atomicAdd(&acc[rl], p);
    }
    __syncthreads();

    float part = 0.f;
    int gbase = b * RB_SZ;
    for (int k = t; k < RB_SZ; k += 1024) {
        float d = acc[k] - z[gbase + k];
        part += d * d;
    }
#pragma unroll
    for (int off = 32; off >= 1; off >>= 1) part += __shfl_xor(part, off, 64);
    if ((t & 63) == 0) red[t >> 6] = part;
    __syncthreads();
    if (t == 0) {
        float s = 0.f;
        for (int k = 0; k < 16; ++k) s += red[k];
        unsafeAtomicAdd(out, s * (1.0f / (float)N_NODES));
    }
}

extern "C" void kernel_launch(void* const* d_in, const int* in_sizes, int n_in,
                              void* d_out, int out_size, void* d_ws, size_t ws_size,
                              hipStream_t stream) {
    const float* diag  = (const float*)d_in[0];
    const float* U     = (const float*)d_in[1];
    const float* V     = (const float*)d_in[2];
    const float* Avals = (const float*)d_in[3];
    const float* z     = (const float*)d_in[4];
    const int*   Aidx  = (const int*)d_in[5];
    const int* rows = Aidx;
    const int* cols = Aidx + NNZ_E;

    char* ws = (char*)d_ws;
    size_t off = 0;
    unsigned short* wb  = (unsigned short*)(ws + off); off += (size_t)N_NODES * 2;       // 8 MiB
    v2u* rowBinned      = (v2u*)(ws + off);            off += (size_t)NB * CAPR * 8;     // 68 MiB
    unsigned* rowCtr    = (unsigned*)(ws + off);       off += 1024;
    float2* M           = (float2*)(ws + off);         off += (size_t)(N_NODES / 256) * 8; // 128 KiB
    float* S            = (float*)(ws + off);          off += 16384;

    hipMemsetAsync(rowCtr, 0, NB * 4, stream);
    kA<<<3072, 512, 0, stream>>>(z, M, S, (float*)d_out, rows, cols, Avals, rowCtr, rowBinned);
    kB<<<80, 256, 0, stream>>>(M, V, S);
    kCw<<<2048, 512, 0, stream>>>(diag, z, S, U, wb);
    kE<<<NB, 1024, 0, stream>>>(rowBinned, rowCtr, wb, z, (float*)d_out);
}